// Round 15
// baseline (221.942 us; speedup 1.0000x reference)
//
#include <hip/hip_runtime.h>
#include <hip/hip_bf16.h>
#include <stdint.h>

#define KDIM 4096
#define NDIM 4096
#define MDIM 4096
#define BM 256
#define BN 256
#define BK 64

typedef __attribute__((ext_vector_type(8))) short bf16x8;
typedef __attribute__((ext_vector_type(4))) float f32x4;

// ---------- helpers ----------

__device__ __forceinline__ unsigned short bf16bits(float f) {
    union { float f; uint32_t u; } c; c.f = f;
    uint32_t u = c.u;
    uint32_t r = (u + 0x7fffu + ((u >> 16) & 1u)) >> 16;   // RNE
    return (unsigned short)r;
}

// Faithful FP4 E2M1 quant-dequant (matches reference float math).
__device__ __forceinline__ float fp4qd(float x) {
    float a = fabsf(x);
    if (a == 0.0f) return 0.0f;
    float e = floorf(log2f(a));
    float val;
    if (e < 0.0f) {                       // subnormal path
        float mant = fminf(fmaxf(rintf(a * 2.0f), 0.0f), 1.0f);
        val = mant * 0.5f;
    } else {
        float ec = fminf(e, 2.0f);
        float p  = exp2f(ec);             // exact: 1,2,4
        float mant = fminf(fmaxf(rintf((a / p - 1.0f) * 2.0f), 0.0f), 1.0f);
        val = (1.0f + 0.5f * mant) * p;
    }
    return (x < 0.0f) ? -val : val;
}

__device__ __forceinline__ void gld16(void* lds, const void* g) {
    __builtin_amdgcn_global_load_lds(
        (const __attribute__((address_space(1))) unsigned int*)g,
        (__attribute__((address_space(3))) unsigned int*)lds,
        16, 0, 0);
}

// ---------- fused prep: x f32->bf16  +  weight fp4-quant-dequant->bf16 ----
__global__ __launch_bounds__(256) void prep_kernel(const float* __restrict__ X,
                                                   const float* __restrict__ W,
                                                   unsigned short* __restrict__ Xb,
                                                   unsigned short* __restrict__ Wq) {
    int bid = blockIdx.x;
    int tid = threadIdx.x;
    if (bid < 16384) {
        size_t i = ((size_t)bid * 256 + tid) * 4;
        float4 v = *(const float4*)(X + i);
        ushort4 o;
        o.x = bf16bits(v.x); o.y = bf16bits(v.y);
        o.z = bf16bits(v.z); o.w = bf16bits(v.w);
        *(ushort4*)(Xb + i) = o;
    } else {
        size_t base = ((size_t)(bid - 16384) * 256 + tid) * 4;
        float4 v = *(const float4*)(W + base);
        float am = fmaxf(fmaxf(fabsf(v.x), fabsf(v.y)),
                         fmaxf(fabsf(v.z), fabsf(v.w)));
        #pragma unroll
        for (int s = 16; s; s >>= 1) am = fmaxf(am, __shfl_xor(am, s));  // 32-lane group
        float scale = (am == 0.0f) ? 1.0f : am / 6.0f;
        ushort4 o;
        o.x = bf16bits(fp4qd(v.x / scale) * scale);
        o.y = bf16bits(fp4qd(v.y / scale) * scale);
        o.z = bf16bits(fp4qd(v.z / scale) * scale);
        o.w = bf16bits(fp4qd(v.w / scale) * scale);
        *(ushort4*)(Wq + base) = o;
    }
}

// ---------- GEMM: 256x256-tile, reads one-MFMA-cluster ahead of waits -----
// C = A @ B^T + bias. 8 waves (2M x 4N), per-wave 128x64, acc[8][4].
// LDS: smem[buf][op][half][16KB], 128 KiB dbuf. Chunk-XOR swizzle
// (slot = kc ^ (row&7)); conflict-free ds_read_b128.
// LDS port/K-tile = 192KB reads + 64KB writes ~ 3012cy > MFMA 2483cy ->
// port-bound; target = hide MFMA under LDS service via cluster-ahead reads.
// Per K-tile (1 barrier):
//  alpha: issue avO reads(8) + ALL stages of t+1 (8 gld16); LGKM(8)
//         [waits only front-16 issued one cluster ago]; 32 MFMA
//         -> avO + stage-writes service under this window.
//  beta:  LGKM(0) [avO done; BEFORE BAR => WAR chain for next stages is
//         barrier-ordered]; VM(0) [t+1 stages, slack = alpha cluster];
//         BAR; issue front-16 of t+1 into PARITY-SWAPPED B-reg sets;
//         32 MFMA on current regs -> front-16 services under this window.
// WAR(stage vs t-1 reads): B.LGKM0(avO) < B.BAR < A.BAR < A.next-stage. ✓
// RAW(read vs stage): VM(0)+BAR precede all reads of the staged buffer. ✓
// Wrap tile (t=64) staged+front-read as garbage; results never consumed. ✓

#define BAR()    __builtin_amdgcn_s_barrier()
#define LGKM(n)  asm volatile("s_waitcnt lgkmcnt(" #n ")" ::: "memory")
#define VM0()    asm volatile("s_waitcnt vmcnt(0)" ::: "memory")
#define SCH0()   __builtin_amdgcn_sched_barrier(0)
#define PRIO(x)  __builtin_amdgcn_s_setprio(x)

__global__ __launch_bounds__(512, 2) void gemm256(const unsigned short* __restrict__ A,
                                                  const unsigned short* __restrict__ B,
                                                  const float* __restrict__ bias,
                                                  float* __restrict__ C) {
    __shared__ __attribute__((aligned(16))) char smem[2][2][2][16384];
    char* sm = (char*)&smem[0][0][0][0];

    const int t = threadIdx.x;
    const int l = t & 63;
    const int w = __builtin_amdgcn_readfirstlane(t >> 6);  // 0..7
    const int wm = w >> 2;        // 0..1  (M half)
    const int wn = w & 3;         // 0..3  (N quarter)

    // bijective XCD swizzle (256 blocks, 8 XCDs)
    int bid = blockIdx.x;
    int swz = (bid & 7) * 32 + (bid >> 3);
    int brow = (swz >> 4) * BM;
    int bcol = (swz & 15) * BN;

    // ---- staging addresses (pre-swizzled global source, linear LDS dest) ----
    const int lr8  = l >> 3;
    const int slot = l & 7;
    const int scol = (slot ^ lr8) << 3;
    const unsigned short* pA = A + (size_t)(brow + w * 8 + lr8) * KDIM + scol;
    const unsigned short* pB = B + (size_t)(bcol + w * 8 + lr8) * KDIM + scol;

#define STAGE(b, op, h, kt) do {                                               \
    const unsigned short* _s = ((op) ? pB : pA)                                \
        + (size_t)(h) * 128 * KDIM + (size_t)(kt) * BK;                        \
    gld16(sm + (b) * 65536 + (op) * 32768 + (h) * 16384 + w * 1024, _s);       \
    gld16(sm + (b) * 65536 + (op) * 32768 + (h) * 16384 + 8192 + w * 1024,     \
          _s + (size_t)64 * KDIM);                                             \
} while (0)

    // ---- fragment read addressing ----
    const int fr  = l & 15;
    const int fq  = l >> 4;
    const int kx0 = ((fq    ) ^ (fr & 7)) << 4;
    const int kx1 = ((fq + 4) ^ (fr & 7)) << 4;
    const int frA = fr * 128;

#define RD_A(b, mh, arr) do {                                                   \
    const char* _p = sm + (b) * 65536 + wm * 16384 + (mh) * 8192 + frA;         \
    _Pragma("unroll")                                                           \
    for (int m = 0; m < 4; ++m) {                                               \
        arr[m][0] = *(const bf16x8*)(_p + m * 2048 + kx0);                      \
        arr[m][1] = *(const bf16x8*)(_p + m * 2048 + kx1);                      \
    }                                                                           \
} while (0)

#define RD_B(b, nh, arr) do {                                                   \
    const char* _p = sm + (b) * 65536 + 32768 + wn * 8192 + (nh) * 4096 + frA;  \
    _Pragma("unroll")                                                           \
    for (int n = 0; n < 2; ++n) {                                               \
        arr[n][0] = *(const bf16x8*)(_p + n * 2048 + kx0);                      \
        arr[n][1] = *(const bf16x8*)(_p + n * 2048 + kx1);                      \
    }                                                                           \
} while (0)

    // one mh-half x 4 n-frags x 2 ks = 32 MFMA (ks-outer, independent chains)
#define MMG(mh, AV, BA, BB)                                                     \
    _Pragma("unroll")                                                           \
    for (int ks = 0; ks < 2; ++ks)                                              \
        _Pragma("unroll")                                                       \
        for (int m = 0; m < 4; ++m) {                                           \
            acc[(mh)*4+m][0] = __builtin_amdgcn_mfma_f32_16x16x32_bf16(         \
                AV[m][ks], BA[0][ks], acc[(mh)*4+m][0], 0, 0, 0);               \
            acc[(mh)*4+m][1] = __builtin_amdgcn_mfma_f32_16x16x32_bf16(         \
                AV[m][ks], BA[1][ks], acc[(mh)*4+m][1], 0, 0, 0);               \
            acc[(mh)*4+m][2] = __builtin_amdgcn_mfma_f32_16x16x32_bf16(         \
                AV[m][ks], BB[0][ks], acc[(mh)*4+m][2], 0, 0, 0);               \
            acc[(mh)*4+m][3] = __builtin_amdgcn_mfma_f32_16x16x32_bf16(         \
                AV[m][ks], BB[1][ks], acc[(mh)*4+m][3], 0, 0, 0);               \
        }

    f32x4 acc[8][4];
    #pragma unroll
    for (int m = 0; m < 8; ++m)
        #pragma unroll
        for (int n = 0; n < 4; ++n)
            acc[m][n] = f32x4{0.f, 0.f, 0.f, 0.f};

    bf16x8 avE[4][2], avO[4][2];
    bf16x8 bvAe[2][2], bvBe[2][2], bvAo[2][2], bvBo[2][2];  // parity-swapped

    // one K-tile: buf j (compile-time), current B-regs BAc/BBc, next BAn/BBn
#define TILE_K(j, BAc, BBc, BAn, BBn, kNext) do {                               \
    /* alpha */                                                                 \
    RD_A(j, 1, avO);                                                            \
    STAGE((j)^1, 0, 0, kNext); STAGE((j)^1, 0, 1, kNext);                       \
    STAGE((j)^1, 1, 0, kNext); STAGE((j)^1, 1, 1, kNext);                       \
    LGKM(8); SCH0();                                                            \
    PRIO(1); MMG(0, avE, BAc, BBc); PRIO(0);                                    \
    /* beta */                                                                  \
    LGKM(0); VM0(); BAR(); SCH0();                                              \
    RD_B((j)^1, 0, BAn); RD_B((j)^1, 1, BBn); RD_A((j)^1, 0, avE);              \
    PRIO(1); MMG(1, avO, BAc, BBc); PRIO(0);                                    \
} while (0)

    // ---- prologue: stage tile0 -> buf0; drain; barrier; front-read tile0 ----
    STAGE(0, 0, 0, 0); STAGE(0, 0, 1, 0); STAGE(0, 1, 0, 0); STAGE(0, 1, 1, 0);
    VM0();
    BAR(); SCH0();
    RD_B(0, 0, bvAe); RD_B(0, 1, bvBe); RD_A(0, 0, avE);

    // ---- main loop: 64 K-tiles, x2 unroll for buf index + reg parity ----
    for (int it = 0; it < 32; ++it) {
        const int k1 = 2 * it + 1;
        const int k2 = (2 * it + 2) & 63;   // wraps on last iter (never consumed)
        TILE_K(0, bvAe, bvBe, bvAo, bvBo, k1);
        TILE_K(1, bvAo, bvBo, bvAe, bvBe, k2);
    }

    // ---- epilogue: C[row][col] = acc + bias[col] ----
    // C/D layout: col = lane&15, row = (lane>>4)*4 + reg
    float bb[4];
    #pragma unroll
    for (int n = 0; n < 4; ++n) bb[n] = bias[bcol + wn * 64 + n * 16 + fr];
    #pragma unroll
    for (int mi = 0; mi < 8; ++mi) {
        #pragma unroll
        for (int q = 0; q < 4; ++q) {
            int row = brow + wm * 128 + mi * 16 + fq * 4 + q;
            float* crow = C + (size_t)row * NDIM + bcol + wn * 64;
            #pragma unroll
            for (int n = 0; n < 4; ++n)
                crow[n * 16 + fr] = acc[mi][n][q] + bb[n];
        }
    }
}

// ---------- launch ----------
extern "C" void kernel_launch(void* const* d_in, const int* in_sizes, int n_in,
                              void* d_out, int out_size, void* d_ws, size_t ws_size,
                              hipStream_t stream) {
    const float* x = (const float*)d_in[0];
    const float* w = (const float*)d_in[1];
    const float* b = (const float*)d_in[2];
    float* out = (float*)d_out;

    unsigned short* xb = (unsigned short*)d_ws;                         // 32 MB
    unsigned short* wq = xb + (size_t)NDIM * KDIM;                      // 32 MB

    prep_kernel<<<32768, 256, 0, stream>>>(x, w, xb, wq);
    gemm256<<<(MDIM / BM) * (NDIM / BN), 512, 0, stream>>>(xb, wq, b, out);
}

// Round 16
// 147.717 us; speedup vs baseline: 1.5025x; 1.5025x over previous
//
#include <hip/hip_runtime.h>
#include <hip/hip_bf16.h>
#include <stdint.h>

#define KDIM 4096
#define NDIM 4096
#define MDIM 4096
#define BM 256
#define BN 256
#define BK 64

typedef __attribute__((ext_vector_type(8))) short bf16x8;
typedef __attribute__((ext_vector_type(4))) float f32x4;

// ---------- helpers ----------

__device__ __forceinline__ unsigned short bf16bits(float f) {
    union { float f; uint32_t u; } c; c.f = f;
    uint32_t u = c.u;
    uint32_t r = (u + 0x7fffu + ((u >> 16) & 1u)) >> 16;   // RNE
    return (unsigned short)r;
}

// Faithful FP4 E2M1 quant-dequant (matches reference float math).
__device__ __forceinline__ float fp4qd(float x) {
    float a = fabsf(x);
    if (a == 0.0f) return 0.0f;
    float e = floorf(log2f(a));
    float val;
    if (e < 0.0f) {                       // subnormal path
        float mant = fminf(fmaxf(rintf(a * 2.0f), 0.0f), 1.0f);
        val = mant * 0.5f;
    } else {
        float ec = fminf(e, 2.0f);
        float p  = exp2f(ec);             // exact: 1,2,4
        float mant = fminf(fmaxf(rintf((a / p - 1.0f) * 2.0f), 0.0f), 1.0f);
        val = (1.0f + 0.5f * mant) * p;
    }
    return (x < 0.0f) ? -val : val;
}

__device__ __forceinline__ void gld16(void* lds, const void* g) {
    __builtin_amdgcn_global_load_lds(
        (const __attribute__((address_space(1))) unsigned int*)g,
        (__attribute__((address_space(3))) unsigned int*)lds,
        16, 0, 0);
}

// ---------- fused prep: x f32->bf16  +  weight fp4-quant-dequant->bf16 ----
__global__ __launch_bounds__(256) void prep_kernel(const float* __restrict__ X,
                                                   const float* __restrict__ W,
                                                   unsigned short* __restrict__ Xb,
                                                   unsigned short* __restrict__ Wq) {
    int bid = blockIdx.x;
    int tid = threadIdx.x;
    if (bid < 16384) {
        size_t i = ((size_t)bid * 256 + tid) * 4;
        float4 v = *(const float4*)(X + i);
        ushort4 o;
        o.x = bf16bits(v.x); o.y = bf16bits(v.y);
        o.z = bf16bits(v.z); o.w = bf16bits(v.w);
        *(ushort4*)(Xb + i) = o;
    } else {
        size_t base = ((size_t)(bid - 16384) * 256 + tid) * 4;
        float4 v = *(const float4*)(W + base);
        float am = fmaxf(fmaxf(fabsf(v.x), fabsf(v.y)),
                         fmaxf(fabsf(v.z), fabsf(v.w)));
        #pragma unroll
        for (int s = 16; s; s >>= 1) am = fmaxf(am, __shfl_xor(am, s));  // 32-lane group
        float scale = (am == 0.0f) ? 1.0f : am / 6.0f;
        ushort4 o;
        o.x = bf16bits(fp4qd(v.x / scale) * scale);
        o.y = bf16bits(fp4qd(v.y / scale) * scale);
        o.z = bf16bits(fp4qd(v.z / scale) * scale);
        o.w = bf16bits(fp4qd(v.w / scale) * scale);
        *(ushort4*)(Wq + base) = o;
    }
}

// ---------- GEMM: R11 skeleton + progressive counted-lgkm MFMA splits -----
// C = A @ B^T + bias. 8 waves (2M x 4N), per-wave 128x64, acc[8][4].
// LDS: smem[buf][op][half][16KB], 128 KiB dbuf. Chunk-XOR swizzle
// (slot = kc ^ (row&7)); conflict-free ds_read_b128.
// Memory ops / stages / barriers / vmcnt IDENTICAL to R11 (best measured).
// Only change: each phase's 32-MFMA cluster is split by counted lgkm waits
// so MFMA starts as soon as its operands' reads are serviced (per-wave FIFO):
//  alpha (FIFO: 4 tail-bvA + 8 avE + 4 bvB):
//   LGKM(8) -> 8 MFMA (m01 x bvA); LGKM(4) -> 8 (m23 x bvA);
//   LGKM(0) -> 16 (all-m x bvB)
//  beta (FIFO: 8 avO):
//   LGKM(4) -> 16 MFMA (m01 x bvB,bvA); LGKM(0) -> 16 (m23)
// -> each phase's trailing reads service UNDER the leading MFMA sub-cluster.

#define BAR()    __builtin_amdgcn_s_barrier()
#define LGKM(n)  asm volatile("s_waitcnt lgkmcnt(" #n ")" ::: "memory")
#define VM4()    asm volatile("s_waitcnt vmcnt(4)" ::: "memory")
#define SCH0()   __builtin_amdgcn_sched_barrier(0)
#define PRIO(x)  __builtin_amdgcn_s_setprio(x)

__global__ __launch_bounds__(512, 2) void gemm256(const unsigned short* __restrict__ A,
                                                  const unsigned short* __restrict__ B,
                                                  const float* __restrict__ bias,
                                                  float* __restrict__ C) {
    __shared__ __attribute__((aligned(16))) char smem[2][2][2][16384];
    char* sm = (char*)&smem[0][0][0][0];

    const int t = threadIdx.x;
    const int l = t & 63;
    const int w = __builtin_amdgcn_readfirstlane(t >> 6);  // 0..7
    const int wm = w >> 2;        // 0..1  (M half)
    const int wn = w & 3;         // 0..3  (N quarter)

    // bijective XCD swizzle (256 blocks, 8 XCDs)
    int bid = blockIdx.x;
    int swz = (bid & 7) * 32 + (bid >> 3);
    int brow = (swz >> 4) * BM;
    int bcol = (swz & 15) * BN;

    // ---- staging addresses (pre-swizzled global source, linear LDS dest) ----
    const int lr8  = l >> 3;
    const int slot = l & 7;
    const int scol = (slot ^ lr8) << 3;
    const unsigned short* pA = A + (size_t)(brow + w * 8 + lr8) * KDIM + scol;
    const unsigned short* pB = B + (size_t)(bcol + w * 8 + lr8) * KDIM + scol;

#define STAGE(b, op, h, kt) do {                                               \
    const unsigned short* _s = ((op) ? pB : pA)                                \
        + (size_t)(h) * 128 * KDIM + (size_t)(kt) * BK;                        \
    gld16(sm + (b) * 65536 + (op) * 32768 + (h) * 16384 + w * 1024, _s);       \
    gld16(sm + (b) * 65536 + (op) * 32768 + (h) * 16384 + 8192 + w * 1024,     \
          _s + (size_t)64 * KDIM);                                             \
} while (0)

    // ---- fragment read addressing ----
    const int fr  = l & 15;
    const int fq  = l >> 4;
    const int kx0 = ((fq    ) ^ (fr & 7)) << 4;
    const int kx1 = ((fq + 4) ^ (fr & 7)) << 4;
    const int frA = fr * 128;

#define RD_A(b, mh) do {                                                        \
    const char* _p = sm + (b) * 65536 + wm * 16384 + (mh) * 8192 + frA;         \
    _Pragma("unroll")                                                           \
    for (int m = 0; m < 4; ++m) {                                               \
        av[m][0] = *(const bf16x8*)(_p + m * 2048 + kx0);                       \
        av[m][1] = *(const bf16x8*)(_p + m * 2048 + kx1);                       \
    }                                                                           \
} while (0)

#define RD_B(b, nh, arr) do {                                                   \
    const char* _p = sm + (b) * 65536 + 32768 + wn * 8192 + (nh) * 4096 + frA;  \
    _Pragma("unroll")                                                           \
    for (int n = 0; n < 2; ++n) {                                               \
        arr[n][0] = *(const bf16x8*)(_p + n * 2048 + kx0);                      \
        arr[n][1] = *(const bf16x8*)(_p + n * 2048 + kx1);                      \
    }                                                                           \
} while (0)

// 8-MFMA quarter: rows mlo..mlo+1 of half mh against B-pair arr (ks-outer)
#define MMQ(mh, mlo, arr, nh)                                                   \
    _Pragma("unroll")                                                           \
    for (int ks = 0; ks < 2; ++ks)                                              \
        _Pragma("unroll")                                                       \
        for (int mi2 = 0; mi2 < 2; ++mi2)                                       \
            _Pragma("unroll")                                                   \
            for (int n = 0; n < 2; ++n)                                         \
                acc[(mh) * 4 + (mlo) + mi2][(nh) * 2 + n] =                     \
                    __builtin_amdgcn_mfma_f32_16x16x32_bf16(                    \
                        av[(mlo) + mi2][ks], arr[n][ks],                        \
                        acc[(mh) * 4 + (mlo) + mi2][(nh) * 2 + n], 0, 0, 0);

    f32x4 acc[8][4];
    #pragma unroll
    for (int m = 0; m < 8; ++m)
        #pragma unroll
        for (int n = 0; n < 4; ++n)
            acc[m][n] = f32x4{0.f, 0.f, 0.f, 0.f};

    bf16x8 av[4][2], bvA[2][2], bvB[2][2];

    // ---- prologue: tile0 full (8 gld) + t1.B0 + t1.A0 (4 gld) ----
    STAGE(0, 0, 0, 0); STAGE(0, 0, 1, 0); STAGE(0, 1, 0, 0); STAGE(0, 1, 1, 0);
    STAGE(1, 1, 0, 1); STAGE(1, 0, 0, 1);
    VM4();            // tile0 landed; t1.B0/A0 in flight (4 ops)
    BAR();
    RD_B(0, 0, bvA);  // pre-read t0.B0 (consumed alpha & beta MM(·,0))
    SCH0();

    // ---- main loop: 2 K-tiles / iteration, 2 barriers / K-tile ----
    for (int it = 0; it < 32; ++it) {
        const int k1 = 2 * it + 1;
        const int k2 = (2 * it + 2) & 63;   // wrap on last iter (never read)
        const int k3 = (2 * it + 3) & 63;

        // alpha-even: read buf0 A-mh0 (8) + B-nh1 (4) ; stage t1.A1, t1.B1
        RD_A(0, 0); RD_B(0, 1, bvB);
        STAGE(1, 0, 1, k1); STAGE(1, 1, 1, k1);
        BAR(); LGKM(8); SCH0();
        PRIO(1); MMQ(0, 0, bvA, 0);
        LGKM(4); SCH0(); MMQ(0, 2, bvA, 0);
        LGKM(0); SCH0(); MMQ(0, 0, bvB, 1); MMQ(0, 2, bvB, 1); PRIO(0);
        // beta-even: read buf0 A-mh1 (8) ; stage t2.B0, t2.A0
        RD_A(0, 1);
        STAGE(0, 1, 0, k2); STAGE(0, 0, 0, k2);
        BAR(); LGKM(4); SCH0();
        PRIO(1); MMQ(1, 0, bvB, 1); MMQ(1, 0, bvA, 0);
        LGKM(0); SCH0(); MMQ(1, 2, bvB, 1); MMQ(1, 2, bvA, 0); PRIO(0);
        VM4(); RD_B(1, 0, bvA);   // buf1 (t1) fully landed; tail-read its B0

        // alpha-odd: read buf1 A-mh0 (8) + B-nh1 (4) ; stage t2.A1, t2.B1
        RD_A(1, 0); RD_B(1, 1, bvB);
        STAGE(0, 0, 1, k2); STAGE(0, 1, 1, k2);
        BAR(); LGKM(8); SCH0();
        PRIO(1); MMQ(0, 0, bvA, 0);
        LGKM(4); SCH0(); MMQ(0, 2, bvA, 0);
        LGKM(0); SCH0(); MMQ(0, 0, bvB, 1); MMQ(0, 2, bvB, 1); PRIO(0);
        // beta-odd: read buf1 A-mh1 (8) ; stage t3.B0, t3.A0
        RD_A(1, 1);
        STAGE(1, 1, 0, k3); STAGE(1, 0, 0, k3);
        BAR(); LGKM(4); SCH0();
        PRIO(1); MMQ(1, 0, bvB, 1); MMQ(1, 0, bvA, 0);
        LGKM(0); SCH0(); MMQ(1, 2, bvB, 1); MMQ(1, 2, bvA, 0); PRIO(0);
        VM4(); RD_B(0, 0, bvA);   // buf0 (t2) fully landed; tail-read its B0
    }

    // ---- epilogue: C[row][col] = acc + bias[col] ----
    // C/D layout: col = lane&15, row = (lane>>4)*4 + reg
    float bb[4];
    #pragma unroll
    for (int n = 0; n < 4; ++n) bb[n] = bias[bcol + wn * 64 + n * 16 + fr];
    #pragma unroll
    for (int mi = 0; mi < 8; ++mi) {
        #pragma unroll
        for (int q = 0; q < 4; ++q) {
            int row = brow + wm * 128 + mi * 16 + fq * 4 + q;
            float* crow = C + (size_t)row * NDIM + bcol + wn * 64;
            #pragma unroll
            for (int n = 0; n < 4; ++n)
                crow[n * 16 + fr] = acc[mi][n][q] + bb[n];
        }
    }
}

// ---------- launch ----------
extern "C" void kernel_launch(void* const* d_in, const int* in_sizes, int n_in,
                              void* d_out, int out_size, void* d_ws, size_t ws_size,
                              hipStream_t stream) {
    const float* x = (const float*)d_in[0];
    const float* w = (const float*)d_in[1];
    const float* b = (const float*)d_in[2];
    float* out = (float*)d_out;

    unsigned short* xb = (unsigned short*)d_ws;                         // 32 MB
    unsigned short* wq = xb + (size_t)NDIM * KDIM;                      // 32 MB

    prep_kernel<<<32768, 256, 0, stream>>>(x, w, xb, wq);
    gemm256<<<(MDIM / BM) * (NDIM / BN), 512, 0, stream>>>(xb, wq, b, out);
}

// Round 17
// 147.465 us; speedup vs baseline: 1.5051x; 1.0017x over previous
//
#include <hip/hip_runtime.h>
#include <hip/hip_bf16.h>
#include <stdint.h>

#define KDIM 4096
#define NDIM 4096
#define MDIM 4096
#define BM 256
#define BN 256
#define BK 64

typedef __attribute__((ext_vector_type(8))) short bf16x8;
typedef __attribute__((ext_vector_type(4))) float f32x4;

// ---------- helpers ----------

__device__ __forceinline__ unsigned short bf16bits(float f) {
    union { float f; uint32_t u; } c; c.f = f;
    uint32_t u = c.u;
    uint32_t r = (u + 0x7fffu + ((u >> 16) & 1u)) >> 16;   // RNE
    return (unsigned short)r;
}

// Faithful FP4 E2M1 quant-dequant (matches reference float math).
__device__ __forceinline__ float fp4qd(float x) {
    float a = fabsf(x);
    if (a == 0.0f) return 0.0f;
    float e = floorf(log2f(a));
    float val;
    if (e < 0.0f) {                       // subnormal path
        float mant = fminf(fmaxf(rintf(a * 2.0f), 0.0f), 1.0f);
        val = mant * 0.5f;
    } else {
        float ec = fminf(e, 2.0f);
        float p  = exp2f(ec);             // exact: 1,2,4
        float mant = fminf(fmaxf(rintf((a / p - 1.0f) * 2.0f), 0.0f), 1.0f);
        val = (1.0f + 0.5f * mant) * p;
    }
    return (x < 0.0f) ? -val : val;
}

__device__ __forceinline__ void gld16(void* lds, const void* g) {
    __builtin_amdgcn_global_load_lds(
        (const __attribute__((address_space(1))) unsigned int*)g,
        (__attribute__((address_space(3))) unsigned int*)lds,
        16, 0, 0);
}

// ---------- fused prep: x f32->bf16  +  weight fp4-quant-dequant->bf16 ----
__global__ __launch_bounds__(256) void prep_kernel(const float* __restrict__ X,
                                                   const float* __restrict__ W,
                                                   unsigned short* __restrict__ Xb,
                                                   unsigned short* __restrict__ Wq) {
    int bid = blockIdx.x;
    int tid = threadIdx.x;
    if (bid < 16384) {
        size_t i = ((size_t)bid * 256 + tid) * 4;
        float4 v = *(const float4*)(X + i);
        ushort4 o;
        o.x = bf16bits(v.x); o.y = bf16bits(v.y);
        o.z = bf16bits(v.z); o.w = bf16bits(v.w);
        *(ushort4*)(Xb + i) = o;
    } else {
        size_t base = ((size_t)(bid - 16384) * 256 + tid) * 4;
        float4 v = *(const float4*)(W + base);
        float am = fmaxf(fmaxf(fabsf(v.x), fabsf(v.y)),
                         fmaxf(fabsf(v.z), fabsf(v.w)));
        #pragma unroll
        for (int s = 16; s; s >>= 1) am = fmaxf(am, __shfl_xor(am, s));  // 32-lane group
        float scale = (am == 0.0f) ? 1.0f : am / 6.0f;
        ushort4 o;
        o.x = bf16bits(fp4qd(v.x / scale) * scale);
        o.y = bf16bits(fp4qd(v.y / scale) * scale);
        o.z = bf16bits(fp4qd(v.z / scale) * scale);
        o.w = bf16bits(fp4qd(v.w / scale) * scale);
        *(ushort4*)(Wq + base) = o;
    }
}

// ---------- GEMM: R11 ledger, COMPILER-scheduled lgkm (no manual waits) ---
// C = A @ B^T + bias. 8 waves (2M x 4N), per-wave 128x64, acc[8][4].
// LDS: smem[buf][op][half][16KB], 128 KiB dbuf. Chunk-XOR swizzle
// (slot = kc ^ (row&7)); conflict-free ds_read_b128.
// Memory ops / stages / barriers / vmcnt IDENTICAL to R11 (best measured).
// Change vs R16: ALL manual lgkm waits and mid-phase sched_barriers removed.
// The compiler emits fine-grained lgkmcnt(N) between each ds_read and its
// first consuming MFMA (G7/m97-style), interleaving read service WITH MFMA
// execution instead of serializing [all reads][all MFMA] as R2..R16 did.
// One sched_barrier(0) kept right after each s_barrier: pins reads below
// the barrier, preserving the WAR/RAW audits:
//  - RAW: VM4-counted drains + BAR precede reads of freshly staged buffers.
//  - WAR: each phase's reads are consumed by that phase's MFMAs (compiler
//    waits before last use) BEFORE the phase-end BAR that releases the
//    overwriting stage; tail-read bvA consumed next alpha, re-staged a
//    further full K-tile later (2-barrier + ~900cy landing margin).

#define BAR()    __builtin_amdgcn_s_barrier()
#define VM4()    asm volatile("s_waitcnt vmcnt(4)" ::: "memory")
#define SCH0()   __builtin_amdgcn_sched_barrier(0)
#define PRIO(x)  __builtin_amdgcn_s_setprio(x)

__global__ __launch_bounds__(512, 2) void gemm256(const unsigned short* __restrict__ A,
                                                  const unsigned short* __restrict__ B,
                                                  const float* __restrict__ bias,
                                                  float* __restrict__ C) {
    __shared__ __attribute__((aligned(16))) char smem[2][2][2][16384];
    char* sm = (char*)&smem[0][0][0][0];

    const int t = threadIdx.x;
    const int l = t & 63;
    const int w = __builtin_amdgcn_readfirstlane(t >> 6);  // 0..7
    const int wm = w >> 2;        // 0..1  (M half)
    const int wn = w & 3;         // 0..3  (N quarter)

    // bijective XCD swizzle (256 blocks, 8 XCDs)
    int bid = blockIdx.x;
    int swz = (bid & 7) * 32 + (bid >> 3);
    int brow = (swz >> 4) * BM;
    int bcol = (swz & 15) * BN;

    // ---- staging addresses (pre-swizzled global source, linear LDS dest) ----
    const int lr8  = l >> 3;
    const int slot = l & 7;
    const int scol = (slot ^ lr8) << 3;
    const unsigned short* pA = A + (size_t)(brow + w * 8 + lr8) * KDIM + scol;
    const unsigned short* pB = B + (size_t)(bcol + w * 8 + lr8) * KDIM + scol;

#define STAGE(b, op, h, kt) do {                                               \
    const unsigned short* _s = ((op) ? pB : pA)                                \
        + (size_t)(h) * 128 * KDIM + (size_t)(kt) * BK;                        \
    gld16(sm + (b) * 65536 + (op) * 32768 + (h) * 16384 + w * 1024, _s);       \
    gld16(sm + (b) * 65536 + (op) * 32768 + (h) * 16384 + 8192 + w * 1024,     \
          _s + (size_t)64 * KDIM);                                             \
} while (0)

    // ---- fragment read addressing ----
    const int fr  = l & 15;
    const int fq  = l >> 4;
    const int kx0 = ((fq    ) ^ (fr & 7)) << 4;
    const int kx1 = ((fq + 4) ^ (fr & 7)) << 4;
    const int frA = fr * 128;

#define RD_A(b, mh) do {                                                        \
    const char* _p = sm + (b) * 65536 + wm * 16384 + (mh) * 8192 + frA;         \
    _Pragma("unroll")                                                           \
    for (int m = 0; m < 4; ++m) {                                               \
        av[m][0] = *(const bf16x8*)(_p + m * 2048 + kx0);                       \
        av[m][1] = *(const bf16x8*)(_p + m * 2048 + kx1);                       \
    }                                                                           \
} while (0)

#define RD_B(b, nh, arr) do {                                                   \
    const char* _p = sm + (b) * 65536 + 32768 + wn * 8192 + (nh) * 4096 + frA;  \
    _Pragma("unroll")                                                           \
    for (int n = 0; n < 2; ++n) {                                               \
        arr[n][0] = *(const bf16x8*)(_p + n * 2048 + kx0);                      \
        arr[n][1] = *(const bf16x8*)(_p + n * 2048 + kx1);                      \
    }                                                                           \
} while (0)

// ks-outer: 8 independent MFMAs (distinct acc), then 8 (breaks dep pairs)
#define MM(mh, nh, B_)                                                          \
    _Pragma("unroll")                                                           \
    for (int ks = 0; ks < 2; ++ks)                                              \
        _Pragma("unroll")                                                       \
        for (int m = 0; m < 4; ++m)                                             \
            _Pragma("unroll")                                                   \
            for (int n = 0; n < 2; ++n)                                         \
                acc[(mh) * 4 + m][(nh) * 2 + n] =                               \
                    __builtin_amdgcn_mfma_f32_16x16x32_bf16(                    \
                        av[m][ks], B_[n][ks], acc[(mh) * 4 + m][(nh) * 2 + n],  \
                        0, 0, 0);

    f32x4 acc[8][4];
    #pragma unroll
    for (int m = 0; m < 8; ++m)
        #pragma unroll
        for (int n = 0; n < 4; ++n)
            acc[m][n] = f32x4{0.f, 0.f, 0.f, 0.f};

    bf16x8 av[4][2], bvA[2][2], bvB[2][2];

    // ---- prologue: tile0 full (8 gld) + t1.B0 + t1.A0 (4 gld) ----
    STAGE(0, 0, 0, 0); STAGE(0, 0, 1, 0); STAGE(0, 1, 0, 0); STAGE(0, 1, 1, 0);
    STAGE(1, 1, 0, 1); STAGE(1, 0, 0, 1);
    VM4();            // tile0 landed; t1.B0/A0 in flight (4 ops)
    BAR(); SCH0();
    RD_B(0, 0, bvA);  // pre-read t0.B0 (consumed alpha & beta MM(·,0))

    // ---- main loop: 2 K-tiles / iteration, 2 barriers / K-tile ----
    for (int it = 0; it < 32; ++it) {
        const int k1 = 2 * it + 1;
        const int k2 = (2 * it + 2) & 63;   // wrap on last iter (never read)
        const int k3 = (2 * it + 3) & 63;

        // alpha-even: read buf0 A-mh0 (8) + B-nh1 (4) ; stage t1.A1, t1.B1
        RD_A(0, 0); RD_B(0, 1, bvB);
        STAGE(1, 0, 1, k1); STAGE(1, 1, 1, k1);
        BAR(); SCH0();
        PRIO(1); MM(0, 0, bvA); MM(0, 1, bvB); PRIO(0);
        // beta-even: read buf0 A-mh1 (8) ; stage t2.B0, t2.A0
        RD_A(0, 1);
        STAGE(0, 1, 0, k2); STAGE(0, 0, 0, k2);
        BAR(); SCH0();
        PRIO(1); MM(1, 1, bvB); MM(1, 0, bvA); PRIO(0);
        VM4(); RD_B(1, 0, bvA);   // buf1 (t1) fully landed; tail-read its B0

        // alpha-odd: read buf1 A-mh0 (8) + B-nh1 (4) ; stage t2.A1, t2.B1
        RD_A(1, 0); RD_B(1, 1, bvB);
        STAGE(0, 0, 1, k2); STAGE(0, 1, 1, k2);
        BAR(); SCH0();
        PRIO(1); MM(0, 0, bvA); MM(0, 1, bvB); PRIO(0);
        // beta-odd: read buf1 A-mh1 (8) ; stage t3.B0, t3.A0
        RD_A(1, 1);
        STAGE(1, 1, 0, k3); STAGE(1, 0, 0, k3);
        BAR(); SCH0();
        PRIO(1); MM(1, 1, bvB); MM(1, 0, bvA); PRIO(0);
        VM4(); RD_B(0, 0, bvA);   // buf0 (t2) fully landed; tail-read its B0
    }

    // ---- epilogue: C[row][col] = acc + bias[col] ----
    // C/D layout: col = lane&15, row = (lane>>4)*4 + reg
    float bb[4];
    #pragma unroll
    for (int n = 0; n < 4; ++n) bb[n] = bias[bcol + wn * 64 + n * 16 + fr];
    #pragma unroll
    for (int mi = 0; mi < 8; ++mi) {
        #pragma unroll
        for (int q = 0; q < 4; ++q) {
            int row = brow + wm * 128 + mi * 16 + fq * 4 + q;
            float* crow = C + (size_t)row * NDIM + bcol + wn * 64;
            #pragma unroll
            for (int n = 0; n < 4; ++n)
                crow[n * 16 + fr] = acc[mi][n][q] + bb[n];
        }
    }
}

// ---------- launch ----------
extern "C" void kernel_launch(void* const* d_in, const int* in_sizes, int n_in,
                              void* d_out, int out_size, void* d_ws, size_t ws_size,
                              hipStream_t stream) {
    const float* x = (const float*)d_in[0];
    const float* w = (const float*)d_in[1];
    const float* b = (const float*)d_in[2];
    float* out = (float*)d_out;

    unsigned short* xb = (unsigned short*)d_ws;                         // 32 MB
    unsigned short* wq = xb + (size_t)NDIM * KDIM;                      // 32 MB

    prep_kernel<<<32768, 256, 0, stream>>>(x, w, xb, wq);
    gemm256<<<(MDIM / BM) * (NDIM / BN), 512, 0, stream>>>(xb, wq, b, out);
}